// Round 11
// baseline (37.243 us; speedup 1.0000x reference)
//
#include <hip/hip_runtime.h>

// Problem constants (match reference)
#define BATCH 4
#define QLEN 2048
#define CLEN 2048
#define DIM 512
#define NBLK 256            // 1 block/CU -> co-residency guaranteed w/ headroom
#define BPB 64              // blocks per batch
#define ROWS 32             // context/output rows per block
#define NFIN 8              // finisher slices per batch (64 e's each)

// The reference collapses: einsum 'bqkh,bvha->bqha' has independent k and v,
// and softmax over k sums to exactly 1, so
//   out[b,q,:] = ((sum_cl context[b,cl,:]) @ Wkv[:,D:2D]) @ Wout   for every q.
// query, Wq, mask are dead inputs.
//
// SINGLE kernel. Cross-block handoff via relaxed AGENT-scope atomics to
// DISTINCT addresses + per-batch counters. No cg::grid.sync (R3: 100us/sync),
// no __threadfence (R4: 257us), no contended RMWs (R7: 44us). R7 phase-B/C
// proved relaxed agent atomic load/store round-trips are coherent cross-XCD.
// Work assignment is counter-elected (varies run to run) but each slice's FP
// sequence is fixed -> output bit-deterministic.

typedef unsigned long long u64;

__device__ __forceinline__ float2 u2f(u64 v) {
    union { u64 u; float2 f; } c; c.u = v; return c.f;
}
__device__ __forceinline__ u64 f2u(float x, float y) {
    union { u64 u; float2 f; } c; c.f = make_float2(x, y); return c.u;
}
__device__ __forceinline__ u64 ald(const u64* p) {
    return __hip_atomic_load(p, __ATOMIC_RELAXED, __HIP_MEMORY_SCOPE_AGENT);
}
__device__ __forceinline__ void ast(u64* p, u64 v) {
    __hip_atomic_store(p, v, __ATOMIC_RELAXED, __HIP_MEMORY_SCOPE_AGENT);
}

__global__ __launch_bounds__(256, 2) void k_fused(
    const float* __restrict__ ctx, const float* __restrict__ Wkv,
    const float* __restrict__ Wout, u64* __restrict__ partial_u,
    float* __restrict__ opart, unsigned* __restrict__ ctrA,
    unsigned* __restrict__ ctrB, float4* __restrict__ out)
{
    __shared__ float4 red[256];
    __shared__ float cs[DIM];
    __shared__ float vl[256];
    __shared__ float vsl[64];
    __shared__ float orow[DIM];
    __shared__ unsigned s_old;
    const int blk = blockIdx.x, t = threadIdx.x;
    const int b = blk >> 6, ch = blk & 63;
    const int rg = t >> 7, f4 = t & 127;

    // ---- Phase A: colsum of 32 context rows (16.8 MB read, coalesced) ----
    {
        const float4* src = reinterpret_cast<const float4*>(ctx)
                          + (size_t)(b * CLEN + ch * ROWS + rg) * (DIM / 4) + f4;
        float4 s0 = make_float4(0.f, 0.f, 0.f, 0.f);
        float4 s1 = make_float4(0.f, 0.f, 0.f, 0.f);
#pragma unroll
        for (int i = 0; i < 16; i += 2) {          // rows rg + {0,2,...,30}
            float4 x = src[(size_t)(2 * i) * (DIM / 4)];
            float4 y = src[(size_t)(2 * i + 2) * (DIM / 4)];
            s0.x += x.x; s0.y += x.y; s0.z += x.z; s0.w += x.w;
            s1.x += y.x; s1.y += y.y; s1.z += y.z; s1.w += y.w;
        }
        red[t] = make_float4(s0.x + s1.x, s0.y + s1.y, s0.z + s1.z, s0.w + s1.w);
        __syncthreads();
        if (t < 128) {
            float4 a = red[t], c = red[t + 128];
            u64* dst = partial_u + (size_t)(b * BPB + ch) * 256 + 2 * t;
            ast(dst,     f2u(a.x + c.x, a.y + c.y));
            ast(dst + 1, f2u(a.z + c.z, a.w + c.w));
        }
        __syncthreads();   // per-wave vmcnt(0) before barrier -> stores complete
        if (t == 0)
            s_old = __hip_atomic_fetch_add(&ctrA[b], 1u, __ATOMIC_RELAXED,
                                           __HIP_MEMORY_SCOPE_AGENT);
        __syncthreads();
    }

    // ---- Middle (8 last-finisher blocks per batch) ----
    if (s_old >= BPB - NFIN) {
        const int sl = (int)s_old - (BPB - NFIN);  // e/f slice 0..7
        // wait for this batch's remaining producers
        if (t == 0)
            while (__hip_atomic_load(&ctrA[b], __ATOMIC_RELAXED,
                                     __HIP_MEMORY_SCOPE_AGENT) < BPB)
                __builtin_amdgcn_s_sleep(2);
        __syncthreads();
        // gather csum[b]: 64 partials x 512 f (u64 coherent loads, coalesced)
        {
            const u64* pb = partial_u + (size_t)(b * BPB) * 256 + t;
            float ax = 0.f, ay = 0.f;
#pragma unroll 8
            for (int c = 0; c < BPB; ++c) {
                float2 v = u2f(ald(pb + (size_t)c * 256));
                ax += v.x; ay += v.y;
            }
            cs[2 * t] = ax; cs[2 * t + 1] = ay;
        }
        __syncthreads();
        // vsl[el] = sum_d cs[d] * Wkv[d][DIM + sl*64 + el]
        {
            const int el = t & 63, dg = t >> 6;
            const float* w = Wkv + (size_t)(dg * 128) * (2 * DIM) + DIM + sl * 64 + el;
            float s = 0.f;
#pragma unroll 8
            for (int d0 = 0; d0 < 128; ++d0)
                s += cs[dg * 128 + d0] * w[(size_t)d0 * (2 * DIM)];
            vl[t] = s;
        }
        __syncthreads();
        if (t < 64) vsl[t] = vl[t] + vl[t + 64] + vl[t + 128] + vl[t + 192];
        __syncthreads();
        // opart[sl][b][f] = sum_e vsl[e] * Wout[sl*64+e][f]
#pragma unroll
        for (int half = 0; half < 2; ++half) {
            const int f = half * 256 + t;
            const float* w = Wout + (size_t)(sl * 64) * DIM + f;
            float s = 0.f;
#pragma unroll 8
            for (int e0 = 0; e0 < 64; ++e0) s += vsl[e0] * w[(size_t)e0 * DIM];
            __hip_atomic_store(&opart[(size_t)(sl * BATCH + b) * DIM + f], s,
                               __ATOMIC_RELAXED, __HIP_MEMORY_SCOPE_AGENT);
        }
        __syncthreads();   // drain opart stores
        if (t == 0)
            __hip_atomic_fetch_add(&ctrB[b], 1u, __ATOMIC_RELAXED,
                                   __HIP_MEMORY_SCOPE_AGENT);
    }

    // ---- Phase D: all blocks wait for their batch's 8 slices, then write ----
    if (t == 0)
        while (__hip_atomic_load(&ctrB[b], __ATOMIC_RELAXED,
                                 __HIP_MEMORY_SCOPE_AGENT) < NFIN)
            __builtin_amdgcn_s_sleep(4);
    __syncthreads();
    {
        const u64* ob = reinterpret_cast<const u64*>(opart) + b * 256 + t;
        float ax = 0.f, ay = 0.f;
#pragma unroll
        for (int sl = 0; sl < NFIN; ++sl) {        // 8 coherent u64 loads
            float2 v = u2f(ald(ob + (size_t)sl * BATCH * 256));
            ax += v.x; ay += v.y;
        }
        orow[2 * t] = ax; orow[2 * t + 1] = ay;
    }
    __syncthreads();
    {
        const float4 val = reinterpret_cast<const float4*>(orow)[f4];
        float4* dst = out + (size_t)(b * QLEN + ch * ROWS + rg) * (DIM / 4) + f4;
#pragma unroll
        for (int i = 0; i < 16; ++i)               // rows rg + {0,2,...,30}
            dst[(size_t)(2 * i) * (DIM / 4)] = val;
    }
}

extern "C" void kernel_launch(void* const* d_in, const int* in_sizes, int n_in,
                              void* d_out, int out_size, void* d_ws, size_t ws_size,
                              hipStream_t stream) {
    // inputs: 0=query (unused), 1=context, 2=mask (unused), 3=Wq (unused), 4=Wkv, 5=Wout
    const float* ctx  = (const float*)d_in[1];
    const float* Wkv  = (const float*)d_in[4];
    const float* Wout = (const float*)d_in[5];
    unsigned* ctrA = (unsigned*)d_ws;                       // 16 B
    unsigned* ctrB = ctrA + 4;                              // 16 B
    u64* partial_u = (u64*)((char*)d_ws + 64);              // NBLK*DIM floats = 512 KB
    float* opart   = (float*)((char*)d_ws + 64 + 524288);   // 8*4*512 floats = 64 KB

    hipMemsetAsync(d_ws, 0, 64, stream);  // counters must be zero EVERY call
    k_fused<<<NBLK, 256, 0, stream>>>(ctx, Wkv, Wout, partial_u, opart,
                                      ctrA, ctrB, (float4*)d_out);
}

// Round 12
// 24.956 us; speedup vs baseline: 1.4924x; 1.4924x over previous
//
#include <hip/hip_runtime.h>

// Problem constants (match reference)
#define BATCH 4
#define QLEN 2048
#define CLEN 2048
#define DIM 512
#define NBLK1 1024          // K1/K5 blocks: 4 per CU
#define CPB 256             // chunks per batch (NBLK1 / BATCH)
#define RPC 8               // rows per chunk

// The reference collapses: einsum 'bqkh,bvha->bqha' has independent k and v,
// and softmax over k sums to exactly 1, so
//   out[b,q,:] = ((sum_cl context[b,cl,:]) @ Wkv[:,D:2D]) @ Wout   for every q.
// query, Wq, mask are dead inputs.
//
// Structure = R6 (best: 26.70us; kernel-count is ~free per R6/R8 equality).
// This round: non-temporal loads on the context stream and non-temporal
// stores on the output stream (zero reuse -> skip L2 allocation), middle
// kernels unchanged (L2-hot). In-kernel grid sync is dead (R3/4/7/11).

typedef float f32x4 __attribute__((ext_vector_type(4)));

// ---- K1: partial[blk][d] = sum of its 8 context rows (16.8 MB NT read) ----
__global__ __launch_bounds__(256) void k1_partial(const float* __restrict__ ctx,
                                                  float4* __restrict__ partial) {
    __shared__ f32x4 red[256];
    const int blk = blockIdx.x, t = threadIdx.x;
    const int b = blk >> 8, ch = blk & 255;
    const int rg = t >> 7, f4 = t & 127;
    const f32x4* src = reinterpret_cast<const f32x4*>(ctx)
                     + (size_t)(b * CLEN + ch * RPC) * (DIM / 4);
    f32x4 s = {0.f, 0.f, 0.f, 0.f};
#pragma unroll
    for (int i = 0; i < 4; ++i)                    // 4 independent NT loads
        s += __builtin_nontemporal_load(&src[(size_t)(rg + 2 * i) * (DIM / 4) + f4]);
    red[t] = s;
    __syncthreads();
    if (t < 128) {
        f32x4 v = red[t] + red[t + 128];
        reinterpret_cast<f32x4*>(partial)[(size_t)blk * (DIM / 4) + t] = v;
    }
}

// ---- K2: csum[b][col4] = sum over 256 chunk partials. 512 blocks. ----
__global__ __launch_bounds__(256) void k2_reduce(const float4* __restrict__ partial,
                                                 float4* __restrict__ csum) {
    __shared__ f32x4 red[256];
    const int blk = blockIdx.x, t = threadIdx.x;
    const int b = blk >> 7, f4g = blk & 127;
    red[t] = reinterpret_cast<const f32x4*>(partial)[(size_t)(b * CPB + t) * (DIM / 4) + f4g];
    __syncthreads();
#pragma unroll
    for (int s = 128; s > 0; s >>= 1) {
        if (t < s) red[t] += red[t + s];
        __syncthreads();
    }
    if (t == 0) reinterpret_cast<f32x4*>(csum)[b * (DIM / 4) + f4g] = red[0];
}

// ---- K3: vsum[b][e] = sum_d csum[b][d] * Wkv[d][DIM+e]. 128 blocks. ----
__global__ __launch_bounds__(256) void k3_vsum(const float* __restrict__ csum,
                                               const float* __restrict__ Wkv,
                                               float* __restrict__ vsum) {
    __shared__ float cs[DIM];
    __shared__ float red[256];
    const int blk = blockIdx.x, t = threadIdx.x;
    const int b = blk >> 5, eg = blk & 31;
    for (int j = t; j < DIM; j += 256) cs[j] = csum[b * DIM + j];
    __syncthreads();
    const int el = t & 15, dg = t >> 4;
    const int e = eg * 16 + el;
    const float* w = Wkv + (size_t)dg * (2 * DIM) + DIM + e;   // d = i*16 + dg
    float s = 0.f;
#pragma unroll
    for (int i = 0; i < 32; ++i)
        s += cs[i * 16 + dg] * w[(size_t)i * 16 * (2 * DIM)];
    red[t] = s;
    __syncthreads();
#pragma unroll
    for (int st = 128; st >= 16; st >>= 1) {
        if (t < st) red[t] += red[t + st];
        __syncthreads();
    }
    if (t < 16) vsum[b * DIM + eg * 16 + t] = red[t];
}

// ---- K4: orow[b][f] = sum_e vsum[b][e] * Wout[e][f]. Same structure. ----
__global__ __launch_bounds__(256) void k4_orow(const float* __restrict__ vsum,
                                               const float* __restrict__ Wout,
                                               float* __restrict__ orow) {
    __shared__ float vs[DIM];
    __shared__ float red[256];
    const int blk = blockIdx.x, t = threadIdx.x;
    const int b = blk >> 5, fg = blk & 31;
    for (int j = t; j < DIM; j += 256) vs[j] = vsum[b * DIM + j];
    __syncthreads();
    const int fl = t & 15, eg2 = t >> 4;
    const int f = fg * 16 + fl;
    const float* w = Wout + (size_t)eg2 * DIM + f;             // e = i*16 + eg2
    float s = 0.f;
#pragma unroll
    for (int i = 0; i < 32; ++i)
        s += vs[i * 16 + eg2] * w[(size_t)i * 16 * DIM];
    red[t] = s;
    __syncthreads();
#pragma unroll
    for (int st = 128; st >= 16; st >>= 1) {
        if (t < st) red[t] += red[t + st];
        __syncthreads();
    }
    if (t < 16) orow[b * DIM + fg * 16 + t] = red[t];
}

// ---- K5: out[b,q,:] = orow[b,:] for all q (16.8 MB NT write) ----
__global__ __launch_bounds__(256) void k5_bcast(const float4* __restrict__ orow4,
                                                float4* __restrict__ out) {
    const int blk = blockIdx.x, t = threadIdx.x;
    const int b = blk >> 8, qg = blk & 255;
    const int rg = t >> 7, f4 = t & 127;
    const f32x4 val = reinterpret_cast<const f32x4*>(orow4)[b * (DIM / 4) + f4];
    f32x4* dst = reinterpret_cast<f32x4*>(out)
               + (size_t)(b * QLEN + qg * RPC) * (DIM / 4);
#pragma unroll
    for (int i = 0; i < 4; ++i)
        __builtin_nontemporal_store(val, &dst[(size_t)(rg + 2 * i) * (DIM / 4) + f4]);
}

extern "C" void kernel_launch(void* const* d_in, const int* in_sizes, int n_in,
                              void* d_out, int out_size, void* d_ws, size_t ws_size,
                              hipStream_t stream) {
    // inputs: 0=query (unused), 1=context, 2=mask (unused), 3=Wq (unused), 4=Wkv, 5=Wout
    const float* ctx  = (const float*)d_in[1];
    const float* Wkv  = (const float*)d_in[4];
    const float* Wout = (const float*)d_in[5];
    float* ws = (float*)d_ws;
    float* partial = ws;                                   // NBLK1*DIM = 524288 f
    float* csum    = partial + (size_t)NBLK1 * DIM;        // BATCH*DIM = 2048 f
    float* vsum    = csum + BATCH * DIM;                   // BATCH*DIM
    float* orow    = vsum + BATCH * DIM;                   // BATCH*DIM

    k1_partial<<<NBLK1, 256, 0, stream>>>(ctx, (float4*)partial);
    k2_reduce<<<512, 256, 0, stream>>>((const float4*)partial, (float4*)csum);
    k3_vsum<<<128, 256, 0, stream>>>(csum, Wkv, vsum);
    k4_orow<<<128, 256, 0, stream>>>(vsum, Wout, orow);
    k5_bcast<<<NBLK1, 256, 0, stream>>>((const float4*)orow, (float4*)d_out);
}